// Round 1
// baseline (242.288 us; speedup 1.0000x reference)
//
#include <hip/hip_runtime.h>
#include <hip/hip_bf16.h>

// Problem constants (B,S,E,H fixed by the reference)
#define BB 2
#define SS 2048
#define EE 1024
#define HH 16
#define DHH 64

using bf16x8 = __attribute__((ext_vector_type(8))) __bf16;
using f32x4  = __attribute__((ext_vector_type(4))) float;

#if __has_builtin(__builtin_amdgcn_exp2f)
#define EXP2(x) __builtin_amdgcn_exp2f(x)
#else
#define EXP2(x) __exp2f(x)
#endif

static __device__ __forceinline__ unsigned short f2bf(float f) {
    unsigned int u = __float_as_uint(f);
    u += 0x7FFFu + ((u >> 16) & 1u);   // round-to-nearest-even
    return (unsigned short)(u >> 16);
}

// pack two fp32 -> two bf16 in one uint (v_cvt_pk_bf16_f32 on gfx950)
static __device__ __forceinline__ unsigned int pk2bf(float lo, float hi) {
    union { __hip_bfloat162 h2; unsigned int u; } c;
    c.h2 = __float22bfloat162_rn(float2{lo, hi});
    return c.u;
}

// async global->LDS, 16B per lane; LDS dest = wave-uniform base + lane*16
static __device__ __forceinline__ void async_load16(const void* g, void* l) {
    __builtin_amdgcn_global_load_lds(
        (const __attribute__((address_space(1))) unsigned int*)g,
        (__attribute__((address_space(3))) unsigned int*)l, 16, 0, 0);
}

// ---------------------------------------------------------------------------
// fp32 -> bf16 bulk conversion, one fused launch.
// z 0..3: weights (1024^2, 512 x-blocks) into contiguous Wb.
// z 4..6: activations (4096x1024, 2048 x-blocks) into D0/D1/D2.
// ---------------------------------------------------------------------------
__global__ void cvt_kernel(const float* __restrict__ W0, const float* __restrict__ W1,
                           const float* __restrict__ W2, const float* __restrict__ W3,
                           const float* __restrict__ X0, const float* __restrict__ X1,
                           const float* __restrict__ X2,
                           unsigned short* __restrict__ Wb,
                           unsigned short* __restrict__ D0, unsigned short* __restrict__ D1,
                           unsigned short* __restrict__ D2)
{
    const int z = blockIdx.y;
    const float* src;
    unsigned short* dst;
    if (z < 4) {
        if (blockIdx.x >= 512) return;
        src = (z == 0) ? W0 : (z == 1) ? W1 : (z == 2) ? W2 : W3;
        dst = Wb + (size_t)z * 1048576;
    } else {
        src = (z == 4) ? X0 : (z == 5) ? X1 : X2;
        dst = (z == 4) ? D0 : (z == 5) ? D1 : D2;
    }
    const size_t base = (size_t)blockIdx.x * 2048 + (size_t)threadIdx.x * 8;
    const float4 f0 = *(const float4*)(src + base);
    const float4 f1 = *(const float4*)(src + base + 4);
    uint4 p;
    p.x = pk2bf(f0.x, f0.y); p.y = pk2bf(f0.z, f0.w);
    p.z = pk2bf(f1.x, f1.y); p.w = pk2bf(f1.z, f1.w);
    *(uint4*)(dst + base) = p;
}

// ---------------------------------------------------------------------------
// GEMM: Y[m][n] = sum_k A[m][k] * W[n][k]  (X @ W^T).
// Double-buffered LDS + cross-iteration global_load_lds prefetch, one
// barrier per K-iter. MT x NT tile, BK=32, 256 threads (4 waves, 2x2).
// BF16OUT: Y bf16 scaled by per-z ysc. else: Y fp32 + bias.
// ---------------------------------------------------------------------------
template<int MT, int NT, bool BF16OUT>
__global__ __launch_bounds__(256, 3)
void gemm_xwt(const unsigned short* __restrict__ X0, const unsigned short* __restrict__ X1,
              const unsigned short* __restrict__ X2,
              const unsigned short* __restrict__ W0, const unsigned short* __restrict__ W1,
              const unsigned short* __restrict__ W2,
              void* __restrict__ Y0, void* __restrict__ Y1, void* __restrict__ Y2,
              const float* __restrict__ bias, int M, int N, int K,
              float s0, float s1, float s2)
{
    constexpr int BK = 32;
    constexpr int NI = MT / 32;          // A-frags per wave
    constexpr int NJ = NT / 32;          // B-frags per wave
    // UNPADDED: required by global_load_lds (wave-uniform base + lane*16)
    __shared__ __align__(16) unsigned short As[2][MT * BK];
    __shared__ __align__(16) unsigned short Bs[2][NT * BK];

    const int z = blockIdx.z;
    const unsigned short* __restrict__ X = (z == 0) ? X0 : ((z == 1) ? X1 : X2);
    const unsigned short* __restrict__ W = (z == 0) ? W0 : ((z == 1) ? W1 : W2);
    void* __restrict__ Y                 = (z == 0) ? Y0 : ((z == 1) ? Y1 : Y2);
    const float ysc                      = (z == 0) ? s0 : ((z == 1) ? s1 : s2);

    const int tid  = threadIdx.x;
    const int lane = tid & 63;
    const int wave = tid >> 6;
    const int wm   = (wave >> 1) * (MT / 2);
    const int wn   = (wave & 1) * (NT / 2);
    const int m0   = blockIdx.y * MT;
    const int n0   = blockIdx.x * NT;
    const int l16  = lane & 15;
    const int quad = lane >> 4;

    // async staging: lane i covers row (i>>2), k-chunk (i&3)*8 in a 16-row group
    const int arow = lane >> 2;
    const int akc  = (lane & 3) * 8;

    f32x4 acc[NI][NJ];
    #pragma unroll
    for (int i = 0; i < NI; i++)
        #pragma unroll
        for (int j = 0; j < NJ; j++) acc[i][j] = f32x4{0.f, 0.f, 0.f, 0.f};

    auto stage = [&](int k0, int buf) {
        #pragma unroll
        for (int j = 0; j < NT / 64; j++) {
            const int rr = wave * (NT / 4) + j * 16;
            async_load16(W + (size_t)(n0 + rr + arow) * K + k0 + akc, Bs[buf] + rr * BK);
        }
        #pragma unroll
        for (int j = 0; j < MT / 64; j++) {
            const int rr = wave * (MT / 4) + j * 16;
            async_load16(X + (size_t)(m0 + rr + arow) * K + k0 + akc, As[buf] + rr * BK);
        }
    };

    stage(0, 0);                          // prologue: tile 0 -> buf 0
    const int niter = K / BK;
    for (int i = 0; i < niter; i++) {
        const int cur = i & 1;
        __syncthreads();                  // drains tile-i asyncs (issued 1 phase ago)
        if (i + 1 < niter) stage((i + 1) * BK, cur ^ 1);

        bf16x8 afrag[NI], bfrag[NJ];
        #pragma unroll
        for (int ii = 0; ii < NI; ii++)
            afrag[ii] = *(const bf16x8*)(As[cur] + (wm + ii * 16 + l16) * BK + quad * 8);
        #pragma unroll
        for (int j = 0; j < NJ; j++)
            bfrag[j] = *(const bf16x8*)(Bs[cur] + (wn + j * 16 + l16) * BK + quad * 8);
        #pragma unroll
        for (int ii = 0; ii < NI; ii++)
            #pragma unroll
            for (int j = 0; j < NJ; j++)
                acc[ii][j] = __builtin_amdgcn_mfma_f32_16x16x32_bf16(afrag[ii], bfrag[j], acc[ii][j], 0, 0, 0);
    }

    // Epilogue. C/D layout: col = lane&15, row = quad*4 + reg.
    #pragma unroll
    for (int i = 0; i < NI; i++) {
        #pragma unroll
        for (int j = 0; j < NJ; j++) {
            #pragma unroll
            for (int r = 0; r < 4; r++) {
                const int row = m0 + wm + i * 16 + quad * 4 + r;
                const int col = n0 + wn + j * 16 + l16;
                const float v = acc[i][j][r];
                if (BF16OUT) {
                    ((unsigned short*)Y)[(size_t)row * N + col] = f2bf(v * ysc);
                } else {
                    ((float*)Y)[(size_t)row * N + col] = v + bias[col];
                }
            }
        }
    }
}

// ---------------------------------------------------------------------------
// Mask compaction: softmax weights of masked keys are exactly 0 (exp2(-150)
// underflows), and softmax/PV are permutation-invariant over keys -> drop
// masked columns entirely. ~50% of keys are masked (randint 0..1), halving
// attention work. Order-preserving prefix compaction.
// Grid (32 slot-tiles, 2 batches), 256 threads. Per block:
//   1) block prefix-scan of mask[b] (wave shfl scans + 4-entry combine)
//   2) srcIdx[j] = source key of compacted slot t0+j (-1 = pad, zero-filled)
//   3) gather K rows  Kb -> Kc   (coalesced 2KB row copies)
//   4) gather+transpose V: Vb rows -> LDS tile -> Vtc[(b*EE+e)*SS + slot]
// Tiles with t0 >= nkeep exit (attention never reads them).
// [R13 fix: V-transpose store was uint2 x8 = 32 shorts -- half the 64-slot
//  row; slots 32..63 kept 0xAA poison -> absmax 0.12. Now uint4 x8 = 64.]
// ---------------------------------------------------------------------------
__global__ __launch_bounds__(256, 1)
void compact_kernel(const unsigned short* __restrict__ Kb,
                    const unsigned short* __restrict__ Vb,
                    const int* __restrict__ mask,
                    unsigned short* __restrict__ Kc,
                    unsigned short* __restrict__ Vtc)
{
    constexpr int LDE = 264;                 // 256-e chunk + pad
    __shared__ int srcIdx[64];
    __shared__ int wsum[4];
    __shared__ __align__(16) unsigned short T[64 * LDE];

    const int tid  = threadIdx.x;
    const int lane = tid & 63;
    const int wave = tid >> 6;
    const int b    = blockIdx.y;
    const int t0   = blockIdx.x * 64;

    // per-thread chunk of 8 mask entries
    const int base = tid * 8;
    int v[8]; int run = 0;
    #pragma unroll
    for (int i = 0; i < 8; i++) { v[i] = (mask[b * SS + base + i] != 0) ? 1 : 0; run += v[i]; }

    // wave-inclusive scan of per-thread totals
    int inc = run;
    #pragma unroll
    for (int d = 1; d < 64; d <<= 1) {
        int n = __shfl_up(inc, d, 64);
        if (lane >= d) inc += n;
    }
    if (lane == 63) wsum[wave] = inc;
    __syncthreads();
    const int nkeep = wsum[0] + wsum[1] + wsum[2] + wsum[3];
    if (t0 >= nkeep) return;                 // uniform exit

    if (tid < 64) srcIdx[tid] = -1;
    __syncthreads();

    int r = inc - run;                       // exclusive prefix
    #pragma unroll
    for (int w = 0; w < 4; w++) if (w < wave) r += wsum[w];
    #pragma unroll
    for (int i = 0; i < 8; i++) {
        if (v[i]) {
            if (r >= t0 && r < t0 + 64) srcIdx[r - t0] = base + i;
            r++;
        }
    }
    __syncthreads();

    // K row gather: 64 rows x 2KB, 4 threads/row x 512B
    {
        const int j = tid >> 2, part = tid & 3;
        const int s = srcIdx[j];
        uint4* dst = (uint4*)(Kc + ((size_t)(b * SS + t0 + j)) * EE + part * 256);
        if (s >= 0) {
            const uint4* src = (const uint4*)(Kb + ((size_t)(b * SS + s)) * EE + part * 256);
            #pragma unroll
            for (int c = 0; c < 32; c++) dst[c] = src[c];
        } else {
            #pragma unroll
            for (int c = 0; c < 32; c++) dst[c] = uint4{0, 0, 0, 0};
        }
    }

    // V gather + transpose, 4 chunks of 256 e
    for (int ec = 0; ec < 4; ec++) {
        __syncthreads();
        {
            const int j = tid >> 2, part = tid & 3;
            const int s = srcIdx[j];
            uint4* trow = (uint4*)(T + j * LDE + part * 64);
            if (s >= 0) {
                const uint4* src = (const uint4*)(Vb + ((size_t)(b * SS + s)) * EE + ec * 256 + part * 64);
                #pragma unroll
                for (int c = 0; c < 8; c++) trow[c] = src[c];
            } else {
                #pragma unroll
                for (int c = 0; c < 8; c++) trow[c] = uint4{0, 0, 0, 0};
            }
        }
        __syncthreads();
        {
            const int e = ec * 256 + tid;
            unsigned short* drow = Vtc + ((size_t)(b * EE + e)) * SS + t0;
            unsigned short tmp[64];
            #pragma unroll
            for (int j2 = 0; j2 < 64; j2++) tmp[j2] = T[j2 * LDE + tid];
            #pragma unroll
            for (int c = 0; c < 8; c++) ((uint4*)drow)[c] = ((const uint4*)tmp)[c];  // 8x16B = all 64 slots
        }
    }
}

// ---------------------------------------------------------------------------
// Flash attention v12: occupancy restructure. R12's v11 measured
// OccupancyPercent=16.6 / MfmaUtil=13 / HBM=4.5% -> latency-bound, and the
// limiter was GRID SIZE: 512 blocks x 4 waves = 2048 waves = 2 waves/SIMD,
// nothing to hide the per-tile dependent chain (QK MFMA -> exp2 -> P LDS
// roundtrip -> PV MFMA) behind. v12 halves the per-wave work unit:
//   16 q per wave (1 MFMA q-group) x 4 waves = 64 q/block
//   grid = 32 bh x 32 qblk = 1024 blocks = 4 blocks/CU = 16 waves/CU (2x)
// LDS drops to ~26 KB/block (Ps halves), VGPR drops (~half the acc state),
// so grid is again the only limiter and fills exactly (no tail).
// Everything else (K-tile 64, strides 68, mask-as-C-init pad bias, exp2
// softmax, register prefetch, XCD swizzle, compacted keys) is unchanged.
// ---------------------------------------------------------------------------
__global__ __launch_bounds__(256, 4)
void attn_kernel(const unsigned short* __restrict__ Qb,
                 const unsigned short* __restrict__ Kc,
                 const unsigned short* __restrict__ Vtc,
                 const int* __restrict__ mask,
                 unsigned short* __restrict__ AO)
{
    constexpr int LDK = 68;  // conflict-free (measured 0 in R4-R12)
    constexpr int LDV = 68;
    constexpr int LDP = 68;
    __shared__ __align__(16) unsigned short Ks[64 * LDK];       // [key][d]
    __shared__ __align__(16) unsigned short Vs[64 * LDV];       // [d][key]
    __shared__ __align__(16) unsigned short Ps[4 * 16 * LDP];   // per-wave [q(16)][key]
    __shared__ __align__(16) float Msf[64];                     // pad bias (0 / -150)
    __shared__ int nk_s;

    const int tid  = threadIdx.x;
    const int lane = tid & 63;
    const int wave = tid >> 6;
    const int l16  = lane & 15;
    const int quad = lane >> 4;

    // XCD-aware decode (validated R10/R12: FETCH 69.7 -> 12.4 MB).
    // 1024 blocks: bh = f(linear&31) bijective, qblk = linear>>5 in 0..31.
    const int linear = blockIdx.x;
    const int bh     = (linear & 7) * 4 + ((linear >> 3) & 3);
    const int qblk   = linear >> 5;
    const int b  = bh >> 4;
    const int h  = bh & 15;
    const int q0 = qblk * 64 + wave * 16;

    // recompute nkeep (must match compact_kernel's count)
    if (tid == 0) nk_s = 0;
    __syncthreads();
    {
        int cnt = 0;
        #pragma unroll
        for (int i = 0; i < 8; i++) cnt += (mask[b * SS + tid * 8 + i] != 0) ? 1 : 0;
        #pragma unroll
        for (int d = 32; d >= 1; d >>= 1) cnt += __shfl_xor(cnt, d, 64);
        if (lane == 0) atomicAdd(&nk_s, cnt);
    }
    __syncthreads();
    const int nkeep  = nk_s;
    const int ntiles = (nkeep + 63) >> 6;

    // Q fragments, 16 q rows (B-operand: lane n=q=l16, k=d=quad*8+j).
    // Pre-scaled by log2e/sqrt(S) in the projection GEMM.
    bf16x8 qf[2];
    {
        const unsigned short* qptr = Qb + (size_t)(b * SS + q0 + l16) * EE + h * DHH;
        qf[0] = *(const bf16x8*)(qptr + quad * 8);
        qf[1] = *(const bf16x8*)(qptr + 32 + quad * 8);
    }

    float lsum = 0.f;
    f32x4 o_acc[4];
    #pragma unroll
    for (int j = 0; j < 4; j++) o_acc[j] = f32x4{0.f, 0.f, 0.f, 0.f};

    unsigned short* Pw = Ps + wave * 16 * LDP;

    // staging: 4 threads per row, 32B each
    const int srow = tid >> 2;          // 0..63
    const int sc   = (tid & 3) * 16;    // elem offset 0,16,32,48

    // ---- register prefetch state (tile t+1 lives here during compute of t)
    uint4 kr0, kr1, vr0, vr1;
    auto gload = [&](int t0) {
        const unsigned short* kg = Kc + (size_t)(b * SS + t0 + srow) * EE + h * DHH + sc;
        kr0 = *(const uint4*)(kg);
        kr1 = *(const uint4*)(kg + 8);
        const unsigned short* vg = Vtc + (size_t)(b * EE + h * DHH + srow) * SS + t0 + sc;
        vr0 = *(const uint4*)(vg);
        vr1 = *(const uint4*)(vg + 8);
    };
    gload(0);

    for (int it = 0; it < ntiles; it++) {
        const int t0 = it * 64;
        __syncthreads();   // prior iteration's Ks/Vs frag reads done
        *(uint4*)(Ks + srow * LDK + sc)     = kr0;
        *(uint4*)(Ks + srow * LDK + sc + 8) = kr1;
        *(uint4*)(Vs + srow * LDV + sc)     = vr0;
        *(uint4*)(Vs + srow * LDV + sc + 8) = vr1;
        if (tid < 64) Msf[tid] = (t0 + tid < nkeep) ? 0.0f : -150.0f;
        __syncthreads();

        // prefetch next tile into registers, overlapped with compute below
        if (it + 1 < ntiles) gload(t0 + 64);

        // S^T tile (64 keys x 16 q): pad bias as MFMA C-init, p = exp2(score).
        #pragma unroll
        for (int nt = 0; nt < 4; nt++) {
            bf16x8 kf0 = *(const bf16x8*)(Ks + (nt * 16 + l16) * LDK + quad * 8);
            bf16x8 kf1 = *(const bf16x8*)(Ks + (nt * 16 + l16) * LDK + 32 + quad * 8);
            const f32x4 cinit = *(const f32x4*)(Msf + nt * 16 + quad * 4);
            f32x4 a = __builtin_amdgcn_mfma_f32_16x16x32_bf16(kf0, qf[0], cinit, 0, 0, 0);
            a = __builtin_amdgcn_mfma_f32_16x16x32_bf16(kf1, qf[1], a, 0, 0, 0);
            const float p0 = EXP2(a[0]);
            const float p1 = EXP2(a[1]);
            const float p2 = EXP2(a[2]);
            const float p3 = EXP2(a[3]);
            lsum += (p0 + p1) + (p2 + p3);
            uint2 pck;
            pck.x = pk2bf(p0, p1);
            pck.y = pk2bf(p2, p3);
            *(uint2*)(Pw + l16 * LDP + nt * 16 + quad * 4) = pck;
        }

        // wave-local: ensure P writes land before P frag reads (no barrier)
        __builtin_amdgcn_s_waitcnt(0xC07F);   // lgkmcnt(0)

        // O^T += V^T . P
        #pragma unroll
        for (int s2 = 0; s2 < 2; s2++) {
            bf16x8 pf = *(const bf16x8*)(Pw + l16 * LDP + s2 * 32 + quad * 8);
            #pragma unroll
            for (int jg = 0; jg < 4; jg++) {
                bf16x8 vf = *(const bf16x8*)(Vs + (jg * 16 + l16) * LDV + s2 * 32 + quad * 8);
                o_acc[jg] = __builtin_amdgcn_mfma_f32_16x16x32_bf16(vf, pf, o_acc[jg], 0, 0, 0);
            }
        }
    }

    // final l reduction + store
    float ls = lsum;
    ls += __shfl_xor(ls, 16, 64);
    ls += __shfl_xor(ls, 32, 64);
    const float rl = 1.0f / ls;
    const size_t orow = (size_t)(b * SS + q0 + l16) * EE + h * DHH;
    #pragma unroll
    for (int jg = 0; jg < 4; jg++) {
        uint2 pck;
        pck.x = pk2bf(o_acc[jg][0] * rl, o_acc[jg][1] * rl);
        pck.y = pk2bf(o_acc[jg][2] * rl, o_acc[jg][3] * rl);
        *(uint2*)(AO + orow + jg * 16 + quad * 4) = pck;
    }
}

// ---------------------------------------------------------------------------
// Aliasing plan (stream order makes every alias race-free):
//   d_out (16 MB): phase1 [Xq 8MB | Xk 8MB] (dead after proj GEMM);
//                  phase2 [Kc 8MB | Vtc 8MB] (compacted K / V^T, dead after
//                  attn); phase3 final GEMM overwrites with the real output.
//   ws (40 MB):    [Wb 8MB | Xv 8MB | Qb 8MB | Kb 8MB | Vb 8MB]
//                  AOb aliases Xv (Xv dead once proj GEMM reads it).
// ---------------------------------------------------------------------------
extern "C" void kernel_launch(void* const* d_in, const int* in_sizes, int n_in,
                              void* d_out, int out_size, void* d_ws, size_t ws_size,
                              hipStream_t stream)
{
    (void)in_sizes; (void)n_in; (void)out_size; (void)ws_size;
    const float* queries = (const float*)d_in[0];
    const float* keys    = (const float*)d_in[1];
    const float* values  = (const float*)d_in[2];
    const int*   mask    = (const int*)d_in[3];
    const float* Wq      = (const float*)d_in[4];
    const float* Wk      = (const float*)d_in[5];
    const float* Wv      = (const float*)d_in[6];
    const float* Wo      = (const float*)d_in[7];
    const float* bo      = (const float*)d_in[8];

    const size_t NE = (size_t)BB * SS * EE;          // 4.19M elements
    const size_t WE = (size_t)EE * EE;               // 1.05M elements

    unsigned short* Xq  = (unsigned short*)d_out;    // 8 MB (scratch phase)
    unsigned short* Xk  = Xq + NE;                   // 8 MB (scratch phase)
    unsigned short* Kc  = (unsigned short*)d_out;    // compacted K (after proj)
    unsigned short* Vtc = Kc + NE;                   // compacted V^T
    unsigned short* Wb  = (unsigned short*)d_ws;     // 8 MB (4 weights bf16)
    unsigned short* Xv  = Wb + 4 * WE;               // 8 MB
    unsigned short* Qb  = Xv + NE;                   // 8 MB (pre-scaled)
    unsigned short* Kb  = Qb + NE;                   // 8 MB
    unsigned short* Vb  = Kb + NE;                   // 8 MB (V rows)
    unsigned short* AOb = Xv;                        // alias: Xv dead after proj GEMM

    const int M = BB * SS, N = EE, K = EE;
    // 1/sqrt(2048) * log2(e): softmax exp computed as exp2 of pre-scaled score
    const float qscale = 0.022097086912079608f * 1.4426950408889634f;

    cvt_kernel<<<dim3(2048, 7), 256, 0, stream>>>(
        Wq, Wk, Wv, Wo, queries, keys, values, Wb, Xq, Xk, Xv);

    dim3 gproj(N / 128, M / 128, 3);
    gemm_xwt<128, 128, true><<<gproj, 256, 0, stream>>>(
        Xq, Xk, Xv, Wb, Wb + WE, Wb + 2 * WE,
        (void*)Qb, (void*)Kb, (void*)Vb, nullptr, M, N, K,
        qscale, 1.0f, 1.0f);

    compact_kernel<<<dim3(SS / 64, BB), 256, 0, stream>>>(Kb, Vb, mask, Kc, Vtc);

    attn_kernel<<<dim3(1024), 256, 0, stream>>>(Qb, Kc, Vtc, mask, AOb);

    dim3 gout(N / 64, M / 64, 1);
    gemm_xwt<64, 64, false><<<gout, 256, 0, stream>>>(
        AOb, AOb, AOb, Wb + 3 * WE, Wb + 3 * WE, Wb + 3 * WE,
        d_out, d_out, d_out, bo, M, N, K, 1.0f, 1.0f, 1.0f);
}

// Round 2
// 221.572 us; speedup vs baseline: 1.0935x; 1.0935x over previous
//
#include <hip/hip_runtime.h>
#include <hip/hip_bf16.h>

// Problem constants (B,S,E,H fixed by the reference)
#define BB 2
#define SS 2048
#define EE 1024
#define HH 16
#define DHH 64

using bf16x8 = __attribute__((ext_vector_type(8))) __bf16;
using f32x4  = __attribute__((ext_vector_type(4))) float;
using f32x16 = __attribute__((ext_vector_type(16))) float;
using uint2v = __attribute__((ext_vector_type(2))) unsigned int;

#if __has_builtin(__builtin_amdgcn_exp2f)
#define EXP2(x) __builtin_amdgcn_exp2f(x)
#else
#define EXP2(x) __exp2f(x)
#endif

static __device__ __forceinline__ unsigned short f2bf(float f) {
    unsigned int u = __float_as_uint(f);
    u += 0x7FFFu + ((u >> 16) & 1u);   // round-to-nearest-even
    return (unsigned short)(u >> 16);
}

// pack two fp32 -> two bf16 in one uint (v_cvt_pk_bf16_f32 on gfx950)
static __device__ __forceinline__ unsigned int pk2bf(float lo, float hi) {
    union { __hip_bfloat162 h2; unsigned int u; } c;
    c.h2 = __float22bfloat162_rn(float2{lo, hi});
    return c.u;
}

// async global->LDS, 16B per lane; LDS dest = wave-uniform base + lane*16
static __device__ __forceinline__ void async_load16(const void* g, void* l) {
    __builtin_amdgcn_global_load_lds(
        (const __attribute__((address_space(1))) unsigned int*)g,
        (__attribute__((address_space(3))) unsigned int*)l, 16, 0, 0);
}

// ---------------------------------------------------------------------------
// fp32 -> bf16 bulk conversion, one fused launch.
// ---------------------------------------------------------------------------
__global__ void cvt_kernel(const float* __restrict__ W0, const float* __restrict__ W1,
                           const float* __restrict__ W2, const float* __restrict__ W3,
                           const float* __restrict__ X0, const float* __restrict__ X1,
                           const float* __restrict__ X2,
                           unsigned short* __restrict__ Wb,
                           unsigned short* __restrict__ D0, unsigned short* __restrict__ D1,
                           unsigned short* __restrict__ D2)
{
    const int z = blockIdx.y;
    const float* src;
    unsigned short* dst;
    if (z < 4) {
        if (blockIdx.x >= 512) return;
        src = (z == 0) ? W0 : (z == 1) ? W1 : (z == 2) ? W2 : W3;
        dst = Wb + (size_t)z * 1048576;
    } else {
        src = (z == 4) ? X0 : (z == 5) ? X1 : X2;
        dst = (z == 4) ? D0 : (z == 5) ? D1 : D2;
    }
    const size_t base = (size_t)blockIdx.x * 2048 + (size_t)threadIdx.x * 8;
    const float4 f0 = *(const float4*)(src + base);
    const float4 f1 = *(const float4*)(src + base + 4);
    uint4 p;
    p.x = pk2bf(f0.x, f0.y); p.y = pk2bf(f0.z, f0.w);
    p.z = pk2bf(f1.x, f1.y); p.w = pk2bf(f1.z, f1.w);
    *(uint4*)(dst + base) = p;
}

// ---------------------------------------------------------------------------
// GEMM: Y[m][n] = sum_k A[m][k] * W[n][k]  (X @ W^T).  (unchanged, proven)
// ---------------------------------------------------------------------------
template<int MT, int NT, bool BF16OUT>
__global__ __launch_bounds__(256, 3)
void gemm_xwt(const unsigned short* __restrict__ X0, const unsigned short* __restrict__ X1,
              const unsigned short* __restrict__ X2,
              const unsigned short* __restrict__ W0, const unsigned short* __restrict__ W1,
              const unsigned short* __restrict__ W2,
              void* __restrict__ Y0, void* __restrict__ Y1, void* __restrict__ Y2,
              const float* __restrict__ bias, int M, int N, int K,
              float s0, float s1, float s2)
{
    constexpr int BK = 32;
    constexpr int NI = MT / 32;
    constexpr int NJ = NT / 32;
    __shared__ __align__(16) unsigned short As[2][MT * BK];
    __shared__ __align__(16) unsigned short Bs[2][NT * BK];

    const int z = blockIdx.z;
    const unsigned short* __restrict__ X = (z == 0) ? X0 : ((z == 1) ? X1 : X2);
    const unsigned short* __restrict__ W = (z == 0) ? W0 : ((z == 1) ? W1 : W2);
    void* __restrict__ Y                 = (z == 0) ? Y0 : ((z == 1) ? Y1 : Y2);
    const float ysc                      = (z == 0) ? s0 : ((z == 1) ? s1 : s2);

    const int tid  = threadIdx.x;
    const int lane = tid & 63;
    const int wave = tid >> 6;
    const int wm   = (wave >> 1) * (MT / 2);
    const int wn   = (wave & 1) * (NT / 2);
    const int m0   = blockIdx.y * MT;
    const int n0   = blockIdx.x * NT;
    const int l16  = lane & 15;
    const int quad = lane >> 4;

    const int arow = lane >> 2;
    const int akc  = (lane & 3) * 8;

    f32x4 acc[NI][NJ];
    #pragma unroll
    for (int i = 0; i < NI; i++)
        #pragma unroll
        for (int j = 0; j < NJ; j++) acc[i][j] = f32x4{0.f, 0.f, 0.f, 0.f};

    auto stage = [&](int k0, int buf) {
        #pragma unroll
        for (int j = 0; j < NT / 64; j++) {
            const int rr = wave * (NT / 4) + j * 16;
            async_load16(W + (size_t)(n0 + rr + arow) * K + k0 + akc, Bs[buf] + rr * BK);
        }
        #pragma unroll
        for (int j = 0; j < MT / 64; j++) {
            const int rr = wave * (MT / 4) + j * 16;
            async_load16(X + (size_t)(m0 + rr + arow) * K + k0 + akc, As[buf] + rr * BK);
        }
    };

    stage(0, 0);
    const int niter = K / BK;
    for (int i = 0; i < niter; i++) {
        const int cur = i & 1;
        __syncthreads();
        if (i + 1 < niter) stage((i + 1) * BK, cur ^ 1);

        bf16x8 afrag[NI], bfrag[NJ];
        #pragma unroll
        for (int ii = 0; ii < NI; ii++)
            afrag[ii] = *(const bf16x8*)(As[cur] + (wm + ii * 16 + l16) * BK + quad * 8);
        #pragma unroll
        for (int j = 0; j < NJ; j++)
            bfrag[j] = *(const bf16x8*)(Bs[cur] + (wn + j * 16 + l16) * BK + quad * 8);
        #pragma unroll
        for (int ii = 0; ii < NI; ii++)
            #pragma unroll
            for (int j = 0; j < NJ; j++)
                acc[ii][j] = __builtin_amdgcn_mfma_f32_16x16x32_bf16(afrag[ii], bfrag[j], acc[ii][j], 0, 0, 0);
    }

    #pragma unroll
    for (int i = 0; i < NI; i++) {
        #pragma unroll
        for (int j = 0; j < NJ; j++) {
            #pragma unroll
            for (int r = 0; r < 4; r++) {
                const int row = m0 + wm + i * 16 + quad * 4 + r;
                const int col = n0 + wn + j * 16 + l16;
                const float v = acc[i][j][r];
                if (BF16OUT) {
                    ((unsigned short*)Y)[(size_t)row * N + col] = f2bf(v * ysc);
                } else {
                    ((float*)Y)[(size_t)row * N + col] = v + bias[col];
                }
            }
        }
    }
}

// ---------------------------------------------------------------------------
// Mask compaction (unchanged, proven).
// ---------------------------------------------------------------------------
__global__ __launch_bounds__(256, 1)
void compact_kernel(const unsigned short* __restrict__ Kb,
                    const unsigned short* __restrict__ Vb,
                    const int* __restrict__ mask,
                    unsigned short* __restrict__ Kc,
                    unsigned short* __restrict__ Vtc)
{
    constexpr int LDE = 264;
    __shared__ int srcIdx[64];
    __shared__ int wsum[4];
    __shared__ __align__(16) unsigned short T[64 * LDE];

    const int tid  = threadIdx.x;
    const int lane = tid & 63;
    const int wave = tid >> 6;
    const int b    = blockIdx.y;
    const int t0   = blockIdx.x * 64;

    const int base = tid * 8;
    int v[8]; int run = 0;
    #pragma unroll
    for (int i = 0; i < 8; i++) { v[i] = (mask[b * SS + base + i] != 0) ? 1 : 0; run += v[i]; }

    int inc = run;
    #pragma unroll
    for (int d = 1; d < 64; d <<= 1) {
        int n = __shfl_up(inc, d, 64);
        if (lane >= d) inc += n;
    }
    if (lane == 63) wsum[wave] = inc;
    __syncthreads();
    const int nkeep = wsum[0] + wsum[1] + wsum[2] + wsum[3];
    if (t0 >= nkeep) return;

    if (tid < 64) srcIdx[tid] = -1;
    __syncthreads();

    int r = inc - run;
    #pragma unroll
    for (int w = 0; w < 4; w++) if (w < wave) r += wsum[w];
    #pragma unroll
    for (int i = 0; i < 8; i++) {
        if (v[i]) {
            if (r >= t0 && r < t0 + 64) srcIdx[r - t0] = base + i;
            r++;
        }
    }
    __syncthreads();

    {
        const int j = tid >> 2, part = tid & 3;
        const int s = srcIdx[j];
        uint4* dst = (uint4*)(Kc + ((size_t)(b * SS + t0 + j)) * EE + part * 256);
        if (s >= 0) {
            const uint4* src = (const uint4*)(Kb + ((size_t)(b * SS + s)) * EE + part * 256);
            #pragma unroll
            for (int c = 0; c < 32; c++) dst[c] = src[c];
        } else {
            #pragma unroll
            for (int c = 0; c < 32; c++) dst[c] = uint4{0, 0, 0, 0};
        }
    }

    for (int ec = 0; ec < 4; ec++) {
        __syncthreads();
        {
            const int j = tid >> 2, part = tid & 3;
            const int s = srcIdx[j];
            uint4* trow = (uint4*)(T + j * LDE + part * 64);
            if (s >= 0) {
                const uint4* src = (const uint4*)(Vb + ((size_t)(b * SS + s)) * EE + ec * 256 + part * 64);
                #pragma unroll
                for (int c = 0; c < 8; c++) trow[c] = src[c];
            } else {
                #pragma unroll
                for (int c = 0; c < 8; c++) trow[c] = uint4{0, 0, 0, 0};
            }
        }
        __syncthreads();
        {
            const int e = ec * 256 + tid;
            unsigned short* drow = Vtc + ((size_t)(b * EE + e)) * SS + t0;
            unsigned short tmp[64];
            #pragma unroll
            for (int j2 = 0; j2 < 64; j2++) tmp[j2] = T[j2 * LDE + tid];
            #pragma unroll
            for (int c = 0; c < 8; c++) ((uint4*)drow)[c] = ((const uint4*)tmp)[c];
        }
    }
}

// ---------------------------------------------------------------------------
// Flash attention v13: 32x32x16 MFMA + in-register softmax (T12 structure).
//
// R14 post-mortem: v12 doubled occupancy (16.6->32.3%) but attn got SLOWER
// (47.2->54.1us, MfmaUtil 13->12.4) -> NOT wave-latency-bound. The binding
// constraint is the serial per-tile chain, dominated by the P LDS roundtrip
// (8 ds_write + lgkmcnt(0) full-wave stall + 4 ds_read per wave-tile).
//
// v13 eliminates it entirely (guide m214 / T12):
//   QK^T swapped: mfma_32x32x16(A=K, B=Q) -> S^T; lane&31 = q, 16 keys/lane
//   (key = (r&3)+8*(r>>2)+4*hi per reg r, hi = lane>>5).
//   P -> bf16 in-register: 8x v_cvt_pk_bf16_f32 + 4x permlane32_swap per
//   32-key block assemble the PV A-frags directly:
//     frag(kc=0) = [s02.x, s13.x, s02.y, s13.y], s02 = swap(pk(p0,p1), pk(p4,p5))
//   PV: mfma_32x32x16(A=P[q][key], B=V^T-frag) -- Vs[d][key] layout gives
//   key-contiguous B reads. No Ps, no Msf, no lgkmcnt stall.
//   Pad keys (last tile only): predicated p=0 (uniform branch).
// Geometry reverted to proven v11: 32 q/wave, 4 waves, 512 blocks.
// DS ops/wave-tile: 32 -> 20. s_setprio(1) wraps MFMA clusters (T5).
// ---------------------------------------------------------------------------
__global__ __launch_bounds__(256, 2)
void attn_kernel(const unsigned short* __restrict__ Qb,
                 const unsigned short* __restrict__ Kc,
                 const unsigned short* __restrict__ Vtc,
                 const int* __restrict__ mask,
                 unsigned short* __restrict__ AO)
{
    constexpr int LDK = 68;  // dword stride 34 -> banks 2l+c, 2-way = free
    constexpr int LDV = 68;
    __shared__ __align__(16) unsigned short Ks[64 * LDK];   // [key][d]
    __shared__ __align__(16) unsigned short Vs[64 * LDV];   // [d][key]
    __shared__ float Lsum[4][32];                           // per-wave 1/l
    __shared__ int nk_s;

    const int tid  = threadIdx.x;
    const int lane = tid & 63;
    const int wave = tid >> 6;
    const int l32  = lane & 31;
    const int hi   = lane >> 5;

    // XCD-aware decode (512 blocks, proven v11 geometry)
    const int linear = blockIdx.x;
    const int bh     = (linear & 7) * 4 + ((linear >> 3) & 3);
    const int qblk   = linear >> 5;
    const int b  = bh >> 4;
    const int h  = bh & 15;
    const int q0 = qblk * 128 + wave * 32;

    // recompute nkeep (must match compact_kernel's count)
    if (tid == 0) nk_s = 0;
    __syncthreads();
    {
        int cnt = 0;
        #pragma unroll
        for (int i = 0; i < 8; i++) cnt += (mask[b * SS + tid * 8 + i] != 0) ? 1 : 0;
        #pragma unroll
        for (int d = 32; d >= 1; d >>= 1) cnt += __shfl_xor(cnt, d, 64);
        if (lane == 0) atomicAdd(&nk_s, cnt);
    }
    __syncthreads();
    const int nkeep  = nk_s;
    const int ntiles = (nkeep + 63) >> 6;

    // Q fragments (B-operand: col=q=l32, k=d = t*16 + hi*8 + j), hoisted.
    // Pre-scaled by log2e/sqrt(S) in the projection GEMM.
    bf16x8 qf[4];
    {
        const unsigned short* qptr = Qb + (size_t)(b * SS + q0 + l32) * EE + h * DHH + hi * 8;
        #pragma unroll
        for (int t = 0; t < 4; t++) qf[t] = *(const bf16x8*)(qptr + t * 16);
    }

    float lsum = 0.f;
    f32x16 o_acc[2];
    #pragma unroll
    for (int d = 0; d < 2; d++)
        #pragma unroll
        for (int r = 0; r < 16; r++) o_acc[d][r] = 0.f;

    // staging: 4 threads per row, 32B each
    const int srow = tid >> 2;
    const int sc   = (tid & 3) * 16;

    // register prefetch state (tile t+1 lives here during compute of t)
    uint4 kr0, kr1, vr0, vr1;
    auto gload = [&](int t0) {
        const unsigned short* kg = Kc + (size_t)(b * SS + t0 + srow) * EE + h * DHH + sc;
        kr0 = *(const uint4*)(kg);
        kr1 = *(const uint4*)(kg + 8);
        const unsigned short* vg = Vtc + (size_t)(b * EE + h * DHH + srow) * SS + t0 + sc;
        vr0 = *(const uint4*)(vg);
        vr1 = *(const uint4*)(vg + 8);
    };
    gload(0);

    for (int it = 0; it < ntiles; it++) {
        const int t0 = it * 64;
        __syncthreads();
        *(uint4*)(Ks + srow * LDK + sc)     = kr0;
        *(uint4*)(Ks + srow * LDK + sc + 8) = kr1;
        *(uint4*)(Vs + srow * LDV + sc)     = vr0;
        *(uint4*)(Vs + srow * LDV + sc + 8) = vr1;
        __syncthreads();

        if (it + 1 < ntiles) gload(t0 + 64);

        const bool full = (t0 + 64 <= nkeep);   // uniform

        #pragma unroll
        for (int blk = 0; blk < 2; blk++) {
            // ---- QK^T (swapped): S^T[key][q], 4 chained MFMAs over d
            f32x16 s;
            __builtin_amdgcn_s_setprio(1);
            {
                bf16x8 kf = *(const bf16x8*)(Ks + (blk * 32 + l32) * LDK + hi * 8);
                f32x16 z;
                #pragma unroll
                for (int r = 0; r < 16; r++) z[r] = 0.f;
                s = __builtin_amdgcn_mfma_f32_32x32x16_bf16(kf, qf[0], z, 0, 0, 0);
            }
            #pragma unroll
            for (int t = 1; t < 4; t++) {
                bf16x8 kf = *(const bf16x8*)(Ks + (blk * 32 + l32) * LDK + t * 16 + hi * 8);
                s = __builtin_amdgcn_mfma_f32_32x32x16_bf16(kf, qf[t], s, 0, 0, 0);
            }
            __builtin_amdgcn_s_setprio(0);

            // ---- softmax numerator: p = exp2(score), pads zeroed (last tile)
            float p[16];
            #pragma unroll
            for (int r = 0; r < 16; r++) p[r] = EXP2(s[r]);
            if (!full) {
                const int keyb = t0 + blk * 32 + 4 * hi;
                #pragma unroll
                for (int r = 0; r < 16; r++)
                    if (keyb + ((r & 3) + 8 * (r >> 2)) >= nkeep) p[r] = 0.f;
            }
            #pragma unroll
            for (int r = 0; r < 16; r += 4)
                lsum += ((p[r] + p[r + 1]) + (p[r + 2] + p[r + 3]));

            // ---- P -> bf16 PV A-frags via cvt_pk + permlane32_swap (T12)
            const unsigned int u0 = pk2bf(p[0],  p[1]);
            const unsigned int u1 = pk2bf(p[2],  p[3]);
            const unsigned int u2 = pk2bf(p[4],  p[5]);
            const unsigned int u3 = pk2bf(p[6],  p[7]);
            const unsigned int u4 = pk2bf(p[8],  p[9]);
            const unsigned int u5 = pk2bf(p[10], p[11]);
            const unsigned int u6 = pk2bf(p[12], p[13]);
            const unsigned int u7 = pk2bf(p[14], p[15]);
            const uint2v s02 = __builtin_amdgcn_permlane32_swap(u0, u2, false, false);
            const uint2v s13 = __builtin_amdgcn_permlane32_swap(u1, u3, false, false);
            const uint2v s46 = __builtin_amdgcn_permlane32_swap(u4, u6, false, false);
            const uint2v s57 = __builtin_amdgcn_permlane32_swap(u5, u7, false, false);

            union { unsigned int u[4]; bf16x8 v; } pa0, pa1;
            pa0.u[0] = s02.x; pa0.u[1] = s13.x; pa0.u[2] = s02.y; pa0.u[3] = s13.y;
            pa1.u[0] = s46.x; pa1.u[1] = s57.x; pa1.u[2] = s46.y; pa1.u[3] = s57.y;

            // ---- PV: O[q][d] += P[q][key] . V[key][d], keys blk*32 + kc*16
            __builtin_amdgcn_s_setprio(1);
            #pragma unroll
            for (int kc = 0; kc < 2; kc++) {
                const bf16x8 pav = (kc == 0) ? pa0.v : pa1.v;
                #pragma unroll
                for (int dblk = 0; dblk < 2; dblk++) {
                    bf16x8 vf = *(const bf16x8*)(Vs + (dblk * 32 + l32) * LDV + blk * 32 + kc * 16 + hi * 8);
                    o_acc[dblk] = __builtin_amdgcn_mfma_f32_32x32x16_bf16(pav, vf, o_acc[dblk], 0, 0, 0);
                }
            }
            __builtin_amdgcn_s_setprio(0);
        }
    }

    // ---- final l reduction: lanes l and l+32 hold disjoint key-halves of q=l32
    {
        float ls = lsum;
        ls += __shfl_xor(ls, 32, 64);
        Lsum[wave][l32] = 1.0f / ls;           // both halves write same value
    }
    __builtin_amdgcn_s_waitcnt(0xC07F);        // lgkmcnt(0), wave-local

    // ---- store: O row q = q0 + (r&3)+8*(r>>2)+4*hi, col d = dblk*32 + l32
    #pragma unroll
    for (int r = 0; r < 16; r++) {
        const int qr = (r & 3) + 8 * (r >> 2) + 4 * hi;
        const float rl = Lsum[wave][qr];
        const size_t orow = (size_t)(b * SS + q0 + qr) * EE + h * DHH + l32;
        AO[orow]      = f2bf(o_acc[0][r] * rl);
        AO[orow + 32] = f2bf(o_acc[1][r] * rl);
    }
}

// ---------------------------------------------------------------------------
// Aliasing plan unchanged.
// ---------------------------------------------------------------------------
extern "C" void kernel_launch(void* const* d_in, const int* in_sizes, int n_in,
                              void* d_out, int out_size, void* d_ws, size_t ws_size,
                              hipStream_t stream)
{
    (void)in_sizes; (void)n_in; (void)out_size; (void)ws_size;
    const float* queries = (const float*)d_in[0];
    const float* keys    = (const float*)d_in[1];
    const float* values  = (const float*)d_in[2];
    const int*   mask    = (const int*)d_in[3];
    const float* Wq      = (const float*)d_in[4];
    const float* Wk      = (const float*)d_in[5];
    const float* Wv      = (const float*)d_in[6];
    const float* Wo      = (const float*)d_in[7];
    const float* bo      = (const float*)d_in[8];

    const size_t NE = (size_t)BB * SS * EE;
    const size_t WE = (size_t)EE * EE;

    unsigned short* Xq  = (unsigned short*)d_out;
    unsigned short* Xk  = Xq + NE;
    unsigned short* Kc  = (unsigned short*)d_out;
    unsigned short* Vtc = Kc + NE;
    unsigned short* Wb  = (unsigned short*)d_ws;
    unsigned short* Xv  = Wb + 4 * WE;
    unsigned short* Qb  = Xv + NE;
    unsigned short* Kb  = Qb + NE;
    unsigned short* Vb  = Kb + NE;
    unsigned short* AOb = Xv;

    const int M = BB * SS, N = EE, K = EE;
    const float qscale = 0.022097086912079608f * 1.4426950408889634f;

    cvt_kernel<<<dim3(2048, 7), 256, 0, stream>>>(
        Wq, Wk, Wv, Wo, queries, keys, values, Wb, Xq, Xk, Xv);

    dim3 gproj(N / 128, M / 128, 3);
    gemm_xwt<128, 128, true><<<gproj, 256, 0, stream>>>(
        Xq, Xk, Xv, Wb, Wb + WE, Wb + 2 * WE,
        (void*)Qb, (void*)Kb, (void*)Vb, nullptr, M, N, K,
        qscale, 1.0f, 1.0f);

    compact_kernel<<<dim3(SS / 64, BB), 256, 0, stream>>>(Kb, Vb, mask, Kc, Vtc);

    attn_kernel<<<dim3(512), 256, 0, stream>>>(Qb, Kc, Vtc, mask, AOb);

    dim3 gout(N / 64, M / 64, 1);
    gemm_xwt<64, 64, false><<<gout, 256, 0, stream>>>(
        AOb, AOb, AOb, Wb + 3 * WE, Wb + 3 * WE, Wb + 3 * WE,
        d_out, d_out, d_out, bo, M, N, K, 1.0f, 1.0f, 1.0f);
}

// Round 3
// 219.586 us; speedup vs baseline: 1.1034x; 1.0090x over previous
//
#include <hip/hip_runtime.h>
#include <hip/hip_bf16.h>

// Problem constants (B,S,E,H fixed by the reference)
#define BB 2
#define SS 2048
#define EE 1024
#define HH 16
#define DHH 64

using bf16x8 = __attribute__((ext_vector_type(8))) __bf16;
using f32x4  = __attribute__((ext_vector_type(4))) float;
using f32x16 = __attribute__((ext_vector_type(16))) float;
using uint2v = __attribute__((ext_vector_type(2))) unsigned int;

#if __has_builtin(__builtin_amdgcn_exp2f)
#define EXP2(x) __builtin_amdgcn_exp2f(x)
#else
#define EXP2(x) __exp2f(x)
#endif

static __device__ __forceinline__ unsigned short f2bf(float f) {
    unsigned int u = __float_as_uint(f);
    u += 0x7FFFu + ((u >> 16) & 1u);   // round-to-nearest-even
    return (unsigned short)(u >> 16);
}

// pack two fp32 -> two bf16 in one uint (v_cvt_pk_bf16_f32 on gfx950)
static __device__ __forceinline__ unsigned int pk2bf(float lo, float hi) {
    union { __hip_bfloat162 h2; unsigned int u; } c;
    c.h2 = __float22bfloat162_rn(float2{lo, hi});
    return c.u;
}

// async global->LDS, 16B per lane; LDS dest = wave-uniform base + lane*16
static __device__ __forceinline__ void async_load16(const void* g, void* l) {
    __builtin_amdgcn_global_load_lds(
        (const __attribute__((address_space(1))) unsigned int*)g,
        (__attribute__((address_space(3))) unsigned int*)l, 16, 0, 0);
}

// ---------------------------------------------------------------------------
// fp32 -> bf16 bulk conversion, one fused launch.
// ---------------------------------------------------------------------------
__global__ void cvt_kernel(const float* __restrict__ W0, const float* __restrict__ W1,
                           const float* __restrict__ W2, const float* __restrict__ W3,
                           const float* __restrict__ X0, const float* __restrict__ X1,
                           const float* __restrict__ X2,
                           unsigned short* __restrict__ Wb,
                           unsigned short* __restrict__ D0, unsigned short* __restrict__ D1,
                           unsigned short* __restrict__ D2)
{
    const int z = blockIdx.y;
    const float* src;
    unsigned short* dst;
    if (z < 4) {
        if (blockIdx.x >= 512) return;
        src = (z == 0) ? W0 : (z == 1) ? W1 : (z == 2) ? W2 : W3;
        dst = Wb + (size_t)z * 1048576;
    } else {
        src = (z == 4) ? X0 : (z == 5) ? X1 : X2;
        dst = (z == 4) ? D0 : (z == 5) ? D1 : D2;
    }
    const size_t base = (size_t)blockIdx.x * 2048 + (size_t)threadIdx.x * 8;
    const float4 f0 = *(const float4*)(src + base);
    const float4 f1 = *(const float4*)(src + base + 4);
    uint4 p;
    p.x = pk2bf(f0.x, f0.y); p.y = pk2bf(f0.z, f0.w);
    p.z = pk2bf(f1.x, f1.y); p.w = pk2bf(f1.z, f1.w);
    *(uint4*)(dst + base) = p;
}

// ---------------------------------------------------------------------------
// GEMM: Y[m][n] = sum_k A[m][k] * W[n][k]  (X @ W^T).
// R15: + T1 XCD-chunked block swizzle. Dispatch order round-robins XCDs
// (xcd = linear%8); without remap the gx x-tiles sharing one A-panel land on
// gx different XCDs -> A re-fetched per XCD (proj FETCH 101 MB vs 30 MB
// ideal, R2 counters). Remap gives XCD k a contiguous (gy/8)-row y-band x
// all x-tiles: per-XCD working set = A-band (1 MB) + full W (2 MB) < 4 MB
// private L2 -> A fetched once device-wide, W once per XCD.
// ---------------------------------------------------------------------------
template<int MT, int NT, bool BF16OUT>
__global__ __launch_bounds__(256, 3)
void gemm_xwt(const unsigned short* __restrict__ X0, const unsigned short* __restrict__ X1,
              const unsigned short* __restrict__ X2,
              const unsigned short* __restrict__ W0, const unsigned short* __restrict__ W1,
              const unsigned short* __restrict__ W2,
              void* __restrict__ Y0, void* __restrict__ Y1, void* __restrict__ Y2,
              const float* __restrict__ bias, int M, int N, int K,
              float s0, float s1, float s2)
{
    constexpr int BK = 32;
    constexpr int NI = MT / 32;
    constexpr int NJ = NT / 32;
    __shared__ __align__(16) unsigned short As[2][MT * BK];
    __shared__ __align__(16) unsigned short Bs[2][NT * BK];

    const int z = blockIdx.z;
    const unsigned short* __restrict__ X = (z == 0) ? X0 : ((z == 1) ? X1 : X2);
    const unsigned short* __restrict__ W = (z == 0) ? W0 : ((z == 1) ? W1 : W2);
    void* __restrict__ Y                 = (z == 0) ? Y0 : ((z == 1) ? Y1 : Y2);
    const float ysc                      = (z == 0) ? s0 : ((z == 1) ? s1 : s2);

    const int tid  = threadIdx.x;
    const int lane = tid & 63;
    const int wave = tid >> 6;
    const int wm   = (wave >> 1) * (MT / 2);
    const int wn   = (wave & 1) * (NT / 2);

    // T1 XCD-chunked swizzle (requires gridDim.y % 8 == 0; holds: gy=32).
    // linear%8 is invariant under the remap's y-major reassignment because
    // gridDim.z slices contribute multiples of gx*gy (divisible by 8).
    const unsigned gx  = gridDim.x;
    const unsigned gy  = gridDim.y;
    const unsigned lin = blockIdx.x + gx * blockIdx.y;
    const unsigned k8  = lin & 7u;           // XCD this block lands on
    const unsigned j   = lin >> 3;           // index within the XCD's chunk
    const int m0 = (int)(k8 * (gy >> 3) + j / gx) * MT;
    const int n0 = (int)(j % gx) * NT;

    const int l16  = lane & 15;
    const int quad = lane >> 4;

    const int arow = lane >> 2;
    const int akc  = (lane & 3) * 8;

    f32x4 acc[NI][NJ];
    #pragma unroll
    for (int i = 0; i < NI; i++)
        #pragma unroll
        for (int j2 = 0; j2 < NJ; j2++) acc[i][j2] = f32x4{0.f, 0.f, 0.f, 0.f};

    auto stage = [&](int k0, int buf) {
        #pragma unroll
        for (int j2 = 0; j2 < NT / 64; j2++) {
            const int rr = wave * (NT / 4) + j2 * 16;
            async_load16(W + (size_t)(n0 + rr + arow) * K + k0 + akc, Bs[buf] + rr * BK);
        }
        #pragma unroll
        for (int j2 = 0; j2 < MT / 64; j2++) {
            const int rr = wave * (MT / 4) + j2 * 16;
            async_load16(X + (size_t)(m0 + rr + arow) * K + k0 + akc, As[buf] + rr * BK);
        }
    };

    stage(0, 0);
    const int niter = K / BK;
    for (int i = 0; i < niter; i++) {
        const int cur = i & 1;
        __syncthreads();
        if (i + 1 < niter) stage((i + 1) * BK, cur ^ 1);

        bf16x8 afrag[NI], bfrag[NJ];
        #pragma unroll
        for (int ii = 0; ii < NI; ii++)
            afrag[ii] = *(const bf16x8*)(As[cur] + (wm + ii * 16 + l16) * BK + quad * 8);
        #pragma unroll
        for (int j2 = 0; j2 < NJ; j2++)
            bfrag[j2] = *(const bf16x8*)(Bs[cur] + (wn + j2 * 16 + l16) * BK + quad * 8);
        #pragma unroll
        for (int ii = 0; ii < NI; ii++)
            #pragma unroll
            for (int j2 = 0; j2 < NJ; j2++)
                acc[ii][j2] = __builtin_amdgcn_mfma_f32_16x16x32_bf16(afrag[ii], bfrag[j2], acc[ii][j2], 0, 0, 0);
    }

    #pragma unroll
    for (int i = 0; i < NI; i++) {
        #pragma unroll
        for (int j2 = 0; j2 < NJ; j2++) {
            #pragma unroll
            for (int r = 0; r < 4; r++) {
                const int row = m0 + wm + i * 16 + quad * 4 + r;
                const int col = n0 + wn + j2 * 16 + l16;
                const float v = acc[i][j2][r];
                if (BF16OUT) {
                    ((unsigned short*)Y)[(size_t)row * N + col] = f2bf(v * ysc);
                } else {
                    ((float*)Y)[(size_t)row * N + col] = v + bias[col];
                }
            }
        }
    }
}

// ---------------------------------------------------------------------------
// Mask compaction (unchanged, proven).
// ---------------------------------------------------------------------------
__global__ __launch_bounds__(256, 1)
void compact_kernel(const unsigned short* __restrict__ Kb,
                    const unsigned short* __restrict__ Vb,
                    const int* __restrict__ mask,
                    unsigned short* __restrict__ Kc,
                    unsigned short* __restrict__ Vtc)
{
    constexpr int LDE = 264;
    __shared__ int srcIdx[64];
    __shared__ int wsum[4];
    __shared__ __align__(16) unsigned short T[64 * LDE];

    const int tid  = threadIdx.x;
    const int lane = tid & 63;
    const int wave = tid >> 6;
    const int b    = blockIdx.y;
    const int t0   = blockIdx.x * 64;

    const int base = tid * 8;
    int v[8]; int run = 0;
    #pragma unroll
    for (int i = 0; i < 8; i++) { v[i] = (mask[b * SS + base + i] != 0) ? 1 : 0; run += v[i]; }

    int inc = run;
    #pragma unroll
    for (int d = 1; d < 64; d <<= 1) {
        int n = __shfl_up(inc, d, 64);
        if (lane >= d) inc += n;
    }
    if (lane == 63) wsum[wave] = inc;
    __syncthreads();
    const int nkeep = wsum[0] + wsum[1] + wsum[2] + wsum[3];
    if (t0 >= nkeep) return;

    if (tid < 64) srcIdx[tid] = -1;
    __syncthreads();

    int r = inc - run;
    #pragma unroll
    for (int w = 0; w < 4; w++) if (w < wave) r += wsum[w];
    #pragma unroll
    for (int i = 0; i < 8; i++) {
        if (v[i]) {
            if (r >= t0 && r < t0 + 64) srcIdx[r - t0] = base + i;
            r++;
        }
    }
    __syncthreads();

    {
        const int j = tid >> 2, part = tid & 3;
        const int s = srcIdx[j];
        uint4* dst = (uint4*)(Kc + ((size_t)(b * SS + t0 + j)) * EE + part * 256);
        if (s >= 0) {
            const uint4* src = (const uint4*)(Kb + ((size_t)(b * SS + s)) * EE + part * 256);
            #pragma unroll
            for (int c = 0; c < 32; c++) dst[c] = src[c];
        } else {
            #pragma unroll
            for (int c = 0; c < 32; c++) dst[c] = uint4{0, 0, 0, 0};
        }
    }

    for (int ec = 0; ec < 4; ec++) {
        __syncthreads();
        {
            const int j = tid >> 2, part = tid & 3;
            const int s = srcIdx[j];
            uint4* trow = (uint4*)(T + j * LDE + part * 64);
            if (s >= 0) {
                const uint4* src = (const uint4*)(Vb + ((size_t)(b * SS + s)) * EE + ec * 256 + part * 64);
                #pragma unroll
                for (int c = 0; c < 8; c++) trow[c] = src[c];
            } else {
                #pragma unroll
                for (int c = 0; c < 8; c++) trow[c] = uint4{0, 0, 0, 0};
            }
        }
        __syncthreads();
        {
            const int e = ec * 256 + tid;
            unsigned short* drow = Vtc + ((size_t)(b * EE + e)) * SS + t0;
            unsigned short tmp[64];
            #pragma unroll
            for (int j2 = 0; j2 < 64; j2++) tmp[j2] = T[j2 * LDE + tid];
            #pragma unroll
            for (int c = 0; c < 8; c++) ((uint4*)drow)[c] = ((const uint4*)tmp)[c];
        }
    }
}

// ---------------------------------------------------------------------------
// Flash attention v13 (unchanged from R2 -- proven): 32x32x16 MFMA,
// swapped QK^T, in-register softmax via cvt_pk + permlane32_swap (T12),
// no P LDS roundtrip, s_setprio around MFMA clusters (T5).
// ---------------------------------------------------------------------------
__global__ __launch_bounds__(256, 2)
void attn_kernel(const unsigned short* __restrict__ Qb,
                 const unsigned short* __restrict__ Kc,
                 const unsigned short* __restrict__ Vtc,
                 const int* __restrict__ mask,
                 unsigned short* __restrict__ AO)
{
    constexpr int LDK = 68;
    constexpr int LDV = 68;
    __shared__ __align__(16) unsigned short Ks[64 * LDK];   // [key][d]
    __shared__ __align__(16) unsigned short Vs[64 * LDV];   // [d][key]
    __shared__ float Lsum[4][32];
    __shared__ int nk_s;

    const int tid  = threadIdx.x;
    const int lane = tid & 63;
    const int wave = tid >> 6;
    const int l32  = lane & 31;
    const int hi   = lane >> 5;

    const int linear = blockIdx.x;
    const int bh     = (linear & 7) * 4 + ((linear >> 3) & 3);
    const int qblk   = linear >> 5;
    const int b  = bh >> 4;
    const int h  = bh & 15;
    const int q0 = qblk * 128 + wave * 32;

    if (tid == 0) nk_s = 0;
    __syncthreads();
    {
        int cnt = 0;
        #pragma unroll
        for (int i = 0; i < 8; i++) cnt += (mask[b * SS + tid * 8 + i] != 0) ? 1 : 0;
        #pragma unroll
        for (int d = 32; d >= 1; d >>= 1) cnt += __shfl_xor(cnt, d, 64);
        if (lane == 0) atomicAdd(&nk_s, cnt);
    }
    __syncthreads();
    const int nkeep  = nk_s;
    const int ntiles = (nkeep + 63) >> 6;

    bf16x8 qf[4];
    {
        const unsigned short* qptr = Qb + (size_t)(b * SS + q0 + l32) * EE + h * DHH + hi * 8;
        #pragma unroll
        for (int t = 0; t < 4; t++) qf[t] = *(const bf16x8*)(qptr + t * 16);
    }

    float lsum = 0.f;
    f32x16 o_acc[2];
    #pragma unroll
    for (int d = 0; d < 2; d++)
        #pragma unroll
        for (int r = 0; r < 16; r++) o_acc[d][r] = 0.f;

    const int srow = tid >> 2;
    const int sc   = (tid & 3) * 16;

    uint4 kr0, kr1, vr0, vr1;
    auto gload = [&](int t0) {
        const unsigned short* kg = Kc + (size_t)(b * SS + t0 + srow) * EE + h * DHH + sc;
        kr0 = *(const uint4*)(kg);
        kr1 = *(const uint4*)(kg + 8);
        const unsigned short* vg = Vtc + (size_t)(b * EE + h * DHH + srow) * SS + t0 + sc;
        vr0 = *(const uint4*)(vg);
        vr1 = *(const uint4*)(vg + 8);
    };
    gload(0);

    for (int it = 0; it < ntiles; it++) {
        const int t0 = it * 64;
        __syncthreads();
        *(uint4*)(Ks + srow * LDK + sc)     = kr0;
        *(uint4*)(Ks + srow * LDK + sc + 8) = kr1;
        *(uint4*)(Vs + srow * LDV + sc)     = vr0;
        *(uint4*)(Vs + srow * LDV + sc + 8) = vr1;
        __syncthreads();

        if (it + 1 < ntiles) gload(t0 + 64);

        const bool full = (t0 + 64 <= nkeep);

        #pragma unroll
        for (int blk = 0; blk < 2; blk++) {
            f32x16 s;
            __builtin_amdgcn_s_setprio(1);
            {
                bf16x8 kf = *(const bf16x8*)(Ks + (blk * 32 + l32) * LDK + hi * 8);
                f32x16 z;
                #pragma unroll
                for (int r = 0; r < 16; r++) z[r] = 0.f;
                s = __builtin_amdgcn_mfma_f32_32x32x16_bf16(kf, qf[0], z, 0, 0, 0);
            }
            #pragma unroll
            for (int t = 1; t < 4; t++) {
                bf16x8 kf = *(const bf16x8*)(Ks + (blk * 32 + l32) * LDK + t * 16 + hi * 8);
                s = __builtin_amdgcn_mfma_f32_32x32x16_bf16(kf, qf[t], s, 0, 0, 0);
            }
            __builtin_amdgcn_s_setprio(0);

            float p[16];
            #pragma unroll
            for (int r = 0; r < 16; r++) p[r] = EXP2(s[r]);
            if (!full) {
                const int keyb = t0 + blk * 32 + 4 * hi;
                #pragma unroll
                for (int r = 0; r < 16; r++)
                    if (keyb + ((r & 3) + 8 * (r >> 2)) >= nkeep) p[r] = 0.f;
            }
            #pragma unroll
            for (int r = 0; r < 16; r += 4)
                lsum += ((p[r] + p[r + 1]) + (p[r + 2] + p[r + 3]));

            const unsigned int u0 = pk2bf(p[0],  p[1]);
            const unsigned int u1 = pk2bf(p[2],  p[3]);
            const unsigned int u2 = pk2bf(p[4],  p[5]);
            const unsigned int u3 = pk2bf(p[6],  p[7]);
            const unsigned int u4 = pk2bf(p[8],  p[9]);
            const unsigned int u5 = pk2bf(p[10], p[11]);
            const unsigned int u6 = pk2bf(p[12], p[13]);
            const unsigned int u7 = pk2bf(p[14], p[15]);
            const uint2v s02 = __builtin_amdgcn_permlane32_swap(u0, u2, false, false);
            const uint2v s13 = __builtin_amdgcn_permlane32_swap(u1, u3, false, false);
            const uint2v s46 = __builtin_amdgcn_permlane32_swap(u4, u6, false, false);
            const uint2v s57 = __builtin_amdgcn_permlane32_swap(u5, u7, false, false);

            union { unsigned int u[4]; bf16x8 v; } pa0, pa1;
            pa0.u[0] = s02.x; pa0.u[1] = s13.x; pa0.u[2] = s02.y; pa0.u[3] = s13.y;
            pa1.u[0] = s46.x; pa1.u[1] = s57.x; pa1.u[2] = s46.y; pa1.u[3] = s57.y;

            __builtin_amdgcn_s_setprio(1);
            #pragma unroll
            for (int kc = 0; kc < 2; kc++) {
                const bf16x8 pav = (kc == 0) ? pa0.v : pa1.v;
                #pragma unroll
                for (int dblk = 0; dblk < 2; dblk++) {
                    bf16x8 vf = *(const bf16x8*)(Vs + (dblk * 32 + l32) * LDV + blk * 32 + kc * 16 + hi * 8);
                    o_acc[dblk] = __builtin_amdgcn_mfma_f32_32x32x16_bf16(pav, vf, o_acc[dblk], 0, 0, 0);
                }
            }
            __builtin_amdgcn_s_setprio(0);
        }
    }

    {
        float ls = lsum;
        ls += __shfl_xor(ls, 32, 64);
        Lsum[wave][l32] = 1.0f / ls;
    }
    __builtin_amdgcn_s_waitcnt(0xC07F);

    #pragma unroll
    for (int r = 0; r < 16; r++) {
        const int qr = (r & 3) + 8 * (r >> 2) + 4 * hi;
        const float rl = Lsum[wave][qr];
        const size_t orow = (size_t)(b * SS + q0 + qr) * EE + h * DHH + l32;
        AO[orow]      = f2bf(o_acc[0][r] * rl);
        AO[orow + 32] = f2bf(o_acc[1][r] * rl);
    }
}

// ---------------------------------------------------------------------------
// Aliasing plan unchanged.
// ---------------------------------------------------------------------------
extern "C" void kernel_launch(void* const* d_in, const int* in_sizes, int n_in,
                              void* d_out, int out_size, void* d_ws, size_t ws_size,
                              hipStream_t stream)
{
    (void)in_sizes; (void)n_in; (void)out_size; (void)ws_size;
    const float* queries = (const float*)d_in[0];
    const float* keys    = (const float*)d_in[1];
    const float* values  = (const float*)d_in[2];
    const int*   mask    = (const int*)d_in[3];
    const float* Wq      = (const float*)d_in[4];
    const float* Wk      = (const float*)d_in[5];
    const float* Wv      = (const float*)d_in[6];
    const float* Wo      = (const float*)d_in[7];
    const float* bo      = (const float*)d_in[8];

    const size_t NE = (size_t)BB * SS * EE;
    const size_t WE = (size_t)EE * EE;

    unsigned short* Xq  = (unsigned short*)d_out;
    unsigned short* Xk  = Xq + NE;
    unsigned short* Kc  = (unsigned short*)d_out;
    unsigned short* Vtc = Kc + NE;
    unsigned short* Wb  = (unsigned short*)d_ws;
    unsigned short* Xv  = Wb + 4 * WE;
    unsigned short* Qb  = Xv + NE;
    unsigned short* Kb  = Qb + NE;
    unsigned short* Vb  = Kb + NE;
    unsigned short* AOb = Xv;

    const int M = BB * SS, N = EE, K = EE;
    const float qscale = 0.022097086912079608f * 1.4426950408889634f;

    cvt_kernel<<<dim3(2048, 7), 256, 0, stream>>>(
        Wq, Wk, Wv, Wo, queries, keys, values, Wb, Xq, Xk, Xv);

    dim3 gproj(N / 128, M / 128, 3);
    gemm_xwt<128, 128, true><<<gproj, 256, 0, stream>>>(
        Xq, Xk, Xv, Wb, Wb + WE, Wb + 2 * WE,
        (void*)Qb, (void*)Kb, (void*)Vb, nullptr, M, N, K,
        qscale, 1.0f, 1.0f);

    compact_kernel<<<dim3(SS / 64, BB), 256, 0, stream>>>(Kb, Vb, mask, Kc, Vtc);

    attn_kernel<<<dim3(512), 256, 0, stream>>>(Qb, Kc, Vtc, mask, AOb);

    // out-GEMM: 128x64 tile (8 MFMA/K-iter vs 4 at 64x64), 512 blocks = 2/CU
    dim3 gout(N / 64, M / 128, 1);
    gemm_xwt<128, 64, false><<<gout, 256, 0, stream>>>(
        AOb, AOb, AOb, Wb + 3 * WE, Wb + 3 * WE, Wb + 3 * WE,
        d_out, d_out, d_out, bo, M, N, K, 1.0f, 1.0f, 1.0f);
}

// Round 5
// 217.751 us; speedup vs baseline: 1.1127x; 1.0084x over previous
//
#include <hip/hip_runtime.h>
#include <hip/hip_bf16.h>

// Problem constants (B,S,E,H fixed by the reference)
#define BB 2
#define SS 2048
#define EE 1024
#define HH 16
#define DHH 64

using bf16x8 = __attribute__((ext_vector_type(8))) __bf16;
using f32x4  = __attribute__((ext_vector_type(4))) float;
using f32x16 = __attribute__((ext_vector_type(16))) float;
using uint2v = __attribute__((ext_vector_type(2))) unsigned int;

#if __has_builtin(__builtin_amdgcn_exp2f)
#define EXP2(x) __builtin_amdgcn_exp2f(x)
#else
#define EXP2(x) __exp2f(x)
#endif

// nkeep[b], written by gather_kernel, read by the proj GEMM's early-exit.
// Kernel-boundary ordering (same stream) makes the handoff safe.
__device__ int g_nkeep[2];

static __device__ __forceinline__ unsigned short f2bf(float f) {
    unsigned int u = __float_as_uint(f);
    u += 0x7FFFu + ((u >> 16) & 1u);   // round-to-nearest-even
    return (unsigned short)(u >> 16);
}

// pack two fp32 -> two bf16 in one uint (v_cvt_pk_bf16_f32 on gfx950)
static __device__ __forceinline__ unsigned int pk2bf(float lo, float hi) {
    union { __hip_bfloat162 h2; unsigned int u; } c;
    c.h2 = __float22bfloat162_rn(float2{lo, hi});
    return c.u;
}

// async global->LDS, 16B per lane; LDS dest = wave-uniform base + lane*16
static __device__ __forceinline__ void async_load16(const void* g, void* l) {
    __builtin_amdgcn_global_load_lds(
        (const __attribute__((address_space(1))) unsigned int*)g,
        (__attribute__((address_space(3))) unsigned int*)l, 16, 0, 0);
}

// ---------------------------------------------------------------------------
// fp32 -> bf16 bulk conversion. R16: keys/values no longer converted here
// (gather_kernel compacts them pre-projection). z 0..3: weights; z 4: queries.
// ---------------------------------------------------------------------------
__global__ void cvt_kernel(const float* __restrict__ W0, const float* __restrict__ W1,
                           const float* __restrict__ W2, const float* __restrict__ W3,
                           const float* __restrict__ Xqs,
                           unsigned short* __restrict__ Wb,
                           unsigned short* __restrict__ Dq)
{
    const int z = blockIdx.y;
    const float* src;
    unsigned short* dst;
    if (z < 4) {
        if (blockIdx.x >= 512) return;
        src = (z == 0) ? W0 : (z == 1) ? W1 : (z == 2) ? W2 : W3;
        dst = Wb + (size_t)z * 1048576;
    } else {
        src = Xqs;
        dst = Dq;
    }
    const size_t base = (size_t)blockIdx.x * 2048 + (size_t)threadIdx.x * 8;
    const float4 f0 = *(const float4*)(src + base);
    const float4 f1 = *(const float4*)(src + base + 4);
    uint4 p;
    p.x = pk2bf(f0.x, f0.y); p.y = pk2bf(f0.z, f0.w);
    p.z = pk2bf(f1.x, f1.y); p.w = pk2bf(f1.z, f1.w);
    *(uint4*)(dst + base) = p;
}

// ---------------------------------------------------------------------------
// R16: pre-projection mask compaction. Row selection commutes with X @ W^T,
// so gather the ~nkeep unmasked KEY/VALUE INPUT rows (fp32) into compacted
// bf16 buffers BEFORE the projection GEMM -> z=1,2 of the proj GEMM do ~half
// the work, and the old post-projection compact_kernel disappears (K comes
// out compacted; V^T is written transposed by the GEMM epilogue).
// Pad rows up to the 128-row GEMM tile boundary are ZEROED (poison could be
// NaN-pattern bf16; NaN*0 = NaN would poison PV accumulators).
// Grid (32 tiles, 2 batches, 2 tensors), 256 thr. Block (0,b,0) publishes
// nkeep[b] to g_nkeep for the GEMM's early-exit.
// ---------------------------------------------------------------------------
__global__ __launch_bounds__(256, 2)
void gather_kernel(const float* __restrict__ Ksrc, const float* __restrict__ Vsrc,
                   const int* __restrict__ mask,
                   unsigned short* __restrict__ Xkc, unsigned short* __restrict__ Xvc)
{
    __shared__ int srcIdx[64];
    __shared__ int wsum[4];

    const int tid  = threadIdx.x;
    const int lane = tid & 63;
    const int wave = tid >> 6;
    const int b    = blockIdx.y;
    const int t0   = blockIdx.x * 64;
    const float* __restrict__ src = blockIdx.z ? Vsrc : Ksrc;
    unsigned short* __restrict__ dst = blockIdx.z ? Xvc : Xkc;

    // per-thread chunk of 8 mask entries
    const int base = tid * 8;
    int v[8]; int run = 0;
    #pragma unroll
    for (int i = 0; i < 8; i++) { v[i] = (mask[b * SS + base + i] != 0) ? 1 : 0; run += v[i]; }

    // wave-inclusive scan of per-thread totals
    int inc = run;
    #pragma unroll
    for (int d = 1; d < 64; d <<= 1) {
        int n = __shfl_up(inc, d, 64);
        if (lane >= d) inc += n;
    }
    if (lane == 63) wsum[wave] = inc;
    __syncthreads();
    const int nkeep = wsum[0] + wsum[1] + wsum[2] + wsum[3];

    if (blockIdx.x == 0 && blockIdx.z == 0 && tid == 0) g_nkeep[b] = nkeep;

    // run pad tiles up to the 128-row GEMM boundary (they zero-fill)
    if (t0 >= ((nkeep + 127) & ~127)) return;

    if (tid < 64) srcIdx[tid] = -1;
    __syncthreads();

    int r = inc - run;                       // exclusive prefix
    #pragma unroll
    for (int w = 0; w < 4; w++) if (w < wave) r += wsum[w];
    #pragma unroll
    for (int i = 0; i < 8; i++) {
        if (v[i]) {
            if (r >= t0 && r < t0 + 64) srcIdx[r - t0] = base + i;
            r++;
        }
    }
    __syncthreads();

    // gather + cvt: 4 threads/row, 256 floats each -> 512B bf16
    const int j = tid >> 2, part = tid & 3;
    const int s = srcIdx[j];
    unsigned short* drow = dst + ((size_t)(b * SS + t0 + j)) * EE + part * 256;
    if (s >= 0) {
        const float* srow = src + ((size_t)(b * SS + s)) * EE + part * 256;
        #pragma unroll
        for (int c = 0; c < 32; c++) {
            const float4 f0 = *(const float4*)(srow + c * 8);
            const float4 f1 = *(const float4*)(srow + c * 8 + 4);
            uint4 p;
            p.x = pk2bf(f0.x, f0.y); p.y = pk2bf(f0.z, f0.w);
            p.z = pk2bf(f1.x, f1.y); p.w = pk2bf(f1.z, f1.w);
            *(uint4*)(drow + c * 8) = p;
        }
    } else {
        #pragma unroll
        for (int c = 0; c < 32; c++) *(uint4*)(drow + c * 8) = uint4{0, 0, 0, 0};
    }
}

// ---------------------------------------------------------------------------
// GEMM: Y[m][n] = sum_k A[m][k] * W[n][k]  (X @ W^T).
// T1 XCD-chunked block swizzle (R15). R16 additions:
//  - z>0 (K/V proj): early-exit blocks whose m-tile lies beyond g_nkeep[b]
//    (inputs are compacted; ~half the tiles vanish).
//  - z==2 (V proj): epilogue stores TRANSPOSED into Vtc[b][e][slot] (uint2 =
//    4 consecutive slots), replacing the old separate transpose kernel.
// ---------------------------------------------------------------------------
template<int MT, int NT, bool BF16OUT>
__global__ __launch_bounds__(256, 3)
void gemm_xwt(const unsigned short* __restrict__ X0, const unsigned short* __restrict__ X1,
              const unsigned short* __restrict__ X2,
              const unsigned short* __restrict__ W0, const unsigned short* __restrict__ W1,
              const unsigned short* __restrict__ W2,
              void* __restrict__ Y0, void* __restrict__ Y1, void* __restrict__ Y2,
              const float* __restrict__ bias, int M, int N, int K,
              float s0, float s1, float s2)
{
    constexpr int BK = 32;
    constexpr int NI = MT / 32;
    constexpr int NJ = NT / 32;
    __shared__ __align__(16) unsigned short As[2][MT * BK];
    __shared__ __align__(16) unsigned short Bs[2][NT * BK];

    const int z = blockIdx.z;
    const unsigned short* __restrict__ X = (z == 0) ? X0 : ((z == 1) ? X1 : X2);
    const unsigned short* __restrict__ W = (z == 0) ? W0 : ((z == 1) ? W1 : W2);
    void* __restrict__ Y                 = (z == 0) ? Y0 : ((z == 1) ? Y1 : Y2);
    const float ysc                      = (z == 0) ? s0 : ((z == 1) ? s1 : s2);

    const int tid  = threadIdx.x;
    const int lane = tid & 63;
    const int wave = tid >> 6;
    const int wm   = (wave >> 1) * (MT / 2);
    const int wn   = (wave & 1) * (NT / 2);

    // T1 XCD-chunked swizzle (gridDim.y % 8 == 0 holds for all call sites)
    const unsigned gx  = gridDim.x;
    const unsigned gy  = gridDim.y;
    const unsigned lin = blockIdx.x + gx * blockIdx.y;
    const unsigned k8  = lin & 7u;
    const unsigned j   = lin >> 3;
    const int m0 = (int)(k8 * (gy >> 3) + j / gx) * MT;
    const int n0 = (int)(j % gx) * NT;

    // R16 early-exit: compacted K/V proj tiles beyond nkeep (block-uniform)
    if (BF16OUT && z > 0) {
        const int bb = m0 >> 11;                // 2048 rows per batch
        if ((m0 & 2047) >= g_nkeep[bb]) return;
    }

    const int l16  = lane & 15;
    const int quad = lane >> 4;

    const int arow = lane >> 2;
    const int akc  = (lane & 3) * 8;

    f32x4 acc[NI][NJ];
    #pragma unroll
    for (int i = 0; i < NI; i++)
        #pragma unroll
        for (int j2 = 0; j2 < NJ; j2++) acc[i][j2] = f32x4{0.f, 0.f, 0.f, 0.f};

    auto stage = [&](int k0, int buf) {
        #pragma unroll
        for (int j2 = 0; j2 < NT / 64; j2++) {
            const int rr = wave * (NT / 4) + j2 * 16;
            async_load16(W + (size_t)(n0 + rr + arow) * K + k0 + akc, Bs[buf] + rr * BK);
        }
        #pragma unroll
        for (int j2 = 0; j2 < MT / 64; j2++) {
            const int rr = wave * (MT / 4) + j2 * 16;
            async_load16(X + (size_t)(m0 + rr + arow) * K + k0 + akc, As[buf] + rr * BK);
        }
    };

    stage(0, 0);
    const int niter = K / BK;
    for (int i = 0; i < niter; i++) {
        const int cur = i & 1;
        __syncthreads();
        if (i + 1 < niter) stage((i + 1) * BK, cur ^ 1);

        bf16x8 afrag[NI], bfrag[NJ];
        #pragma unroll
        for (int ii = 0; ii < NI; ii++)
            afrag[ii] = *(const bf16x8*)(As[cur] + (wm + ii * 16 + l16) * BK + quad * 8);
        #pragma unroll
        for (int j2 = 0; j2 < NJ; j2++)
            bfrag[j2] = *(const bf16x8*)(Bs[cur] + (wn + j2 * 16 + l16) * BK + quad * 8);
        #pragma unroll
        for (int ii = 0; ii < NI; ii++)
            #pragma unroll
            for (int j2 = 0; j2 < NJ; j2++)
                acc[ii][j2] = __builtin_amdgcn_mfma_f32_16x16x32_bf16(afrag[ii], bfrag[j2], acc[ii][j2], 0, 0, 0);
    }

    // Epilogue. C/D layout: col = lane&15, row = quad*4 + reg.
    if (BF16OUT && z == 2) {
        // V proj: store transposed -> Vtc[(b*EE + col)*SS + slot], slot=row%2048.
        // 4 consecutive regs = 4 consecutive slots -> one uint2 (8B) store.
        #pragma unroll
        for (int i = 0; i < NI; i++) {
            #pragma unroll
            for (int j2 = 0; j2 < NJ; j2++) {
                const int row  = m0 + wm + i * 16 + quad * 4;
                const int bb   = row >> 11;
                const int slot = row & 2047;
                const int col  = n0 + wn + j2 * 16 + l16;
                uint2 pck;
                pck.x = pk2bf(acc[i][j2][0], acc[i][j2][1]);
                pck.y = pk2bf(acc[i][j2][2], acc[i][j2][3]);
                *(uint2*)((unsigned short*)Y + ((size_t)(bb * EE + col)) * SS + slot) = pck;
            }
        }
    } else {
        #pragma unroll
        for (int i = 0; i < NI; i++) {
            #pragma unroll
            for (int j2 = 0; j2 < NJ; j2++) {
                #pragma unroll
                for (int r = 0; r < 4; r++) {
                    const int row = m0 + wm + i * 16 + quad * 4 + r;
                    const int col = n0 + wn + j2 * 16 + l16;
                    const float v = acc[i][j2][r];
                    if (BF16OUT) {
                        ((unsigned short*)Y)[(size_t)row * N + col] = f2bf(v * ysc);
                    } else {
                        ((float*)Y)[(size_t)row * N + col] = v + bias[col];
                    }
                }
            }
        }
    }
}

// ---------------------------------------------------------------------------
// Flash attention v13 (unchanged, proven): 32x32x16 MFMA, swapped QK^T,
// in-register softmax via cvt_pk + permlane32_swap (T12), s_setprio (T5).
// Pad slots (>= nkeep) are zero in Kc/Vtc (zero-padded gather -> zero proj
// output) and additionally predicated to p=0 here.
// ---------------------------------------------------------------------------
__global__ __launch_bounds__(256, 2)
void attn_kernel(const unsigned short* __restrict__ Qb,
                 const unsigned short* __restrict__ Kc,
                 const unsigned short* __restrict__ Vtc,
                 const int* __restrict__ mask,
                 unsigned short* __restrict__ AO)
{
    constexpr int LDK = 68;
    constexpr int LDV = 68;
    __shared__ __align__(16) unsigned short Ks[64 * LDK];   // [key][d]
    __shared__ __align__(16) unsigned short Vs[64 * LDV];   // [d][key]
    __shared__ float Lsum[4][32];
    __shared__ int nk_s;

    const int tid  = threadIdx.x;
    const int lane = tid & 63;
    const int wave = tid >> 6;
    const int l32  = lane & 31;
    const int hi   = lane >> 5;

    const int linear = blockIdx.x;
    const int bh     = (linear & 7) * 4 + ((linear >> 3) & 3);
    const int qblk   = linear >> 5;
    const int b  = bh >> 4;
    const int h  = bh & 15;
    const int q0 = qblk * 128 + wave * 32;

    if (tid == 0) nk_s = 0;
    __syncthreads();
    {
        int cnt = 0;
        #pragma unroll
        for (int i = 0; i < 8; i++) cnt += (mask[b * SS + tid * 8 + i] != 0) ? 1 : 0;
        #pragma unroll
        for (int d = 32; d >= 1; d >>= 1) cnt += __shfl_xor(cnt, d, 64);
        if (lane == 0) atomicAdd(&nk_s, cnt);
    }
    __syncthreads();
    const int nkeep  = nk_s;
    const int ntiles = (nkeep + 63) >> 6;

    bf16x8 qf[4];
    {
        const unsigned short* qptr = Qb + (size_t)(b * SS + q0 + l32) * EE + h * DHH + hi * 8;
        #pragma unroll
        for (int t = 0; t < 4; t++) qf[t] = *(const bf16x8*)(qptr + t * 16);
    }

    float lsum = 0.f;
    f32x16 o_acc[2];
    #pragma unroll
    for (int d = 0; d < 2; d++)
        #pragma unroll
        for (int r = 0; r < 16; r++) o_acc[d][r] = 0.f;

    const int srow = tid >> 2;
    const int sc   = (tid & 3) * 16;

    uint4 kr0, kr1, vr0, vr1;
    auto gload = [&](int t0) {
        const unsigned short* kg = Kc + (size_t)(b * SS + t0 + srow) * EE + h * DHH + sc;
        kr0 = *(const uint4*)(kg);
        kr1 = *(const uint4*)(kg + 8);
        const unsigned short* vg = Vtc + (size_t)(b * EE + h * DHH + srow) * SS + t0 + sc;
        vr0 = *(const uint4*)(vg);
        vr1 = *(const uint4*)(vg + 8);
    };
    gload(0);

    for (int it = 0; it < ntiles; it++) {
        const int t0 = it * 64;
        __syncthreads();
        *(uint4*)(Ks + srow * LDK + sc)     = kr0;
        *(uint4*)(Ks + srow * LDK + sc + 8) = kr1;
        *(uint4*)(Vs + srow * LDV + sc)     = vr0;
        *(uint4*)(Vs + srow * LDV + sc + 8) = vr1;
        __syncthreads();

        if (it + 1 < ntiles) gload(t0 + 64);

        const bool full = (t0 + 64 <= nkeep);

        #pragma unroll
        for (int blk = 0; blk < 2; blk++) {
            f32x16 s;
            __builtin_amdgcn_s_setprio(1);
            {
                bf16x8 kf = *(const bf16x8*)(Ks + (blk * 32 + l32) * LDK + hi * 8);
                f32x16 z;
                #pragma unroll
                for (int r = 0; r < 16; r++) z[r] = 0.f;
                s = __builtin_amdgcn_mfma_f32_32x32x16_bf16(kf, qf[0], z, 0, 0, 0);
            }
            #pragma unroll
            for (int t = 1; t < 4; t++) {
                bf16x8 kf = *(const bf16x8*)(Ks + (blk * 32 + l32) * LDK + t * 16 + hi * 8);
                s = __builtin_amdgcn_mfma_f32_32x32x16_bf16(kf, qf[t], s, 0, 0, 0);
            }
            __builtin_amdgcn_s_setprio(0);

            float p[16];
            #pragma unroll
            for (int r = 0; r < 16; r++) p[r] = EXP2(s[r]);
            if (!full) {
                const int keyb = t0 + blk * 32 + 4 * hi;
                #pragma unroll
                for (int r = 0; r < 16; r++)
                    if (keyb + ((r & 3) + 8 * (r >> 2)) >= nkeep) p[r] = 0.f;
            }
            #pragma unroll
            for (int r = 0; r < 16; r += 4)
                lsum += ((p[r] + p[r + 1]) + (p[r + 2] + p[r + 3]));

            const unsigned int u0 = pk2bf(p[0],  p[1]);
            const unsigned int u1 = pk2bf(p[2],  p[3]);
            const unsigned int u2 = pk2bf(p[4],  p[5]);
            const unsigned int u3 = pk2bf(p[6],  p[7]);
            const unsigned int u4 = pk2bf(p[8],  p[9]);
            const unsigned int u5 = pk2bf(p[10], p[11]);
            const unsigned int u6 = pk2bf(p[12], p[13]);
            const unsigned int u7 = pk2bf(p[14], p[15]);
            const uint2v s02 = __builtin_amdgcn_permlane32_swap(u0, u2, false, false);
            const uint2v s13 = __builtin_amdgcn_permlane32_swap(u1, u3, false, false);
            const uint2v s46 = __builtin_amdgcn_permlane32_swap(u4, u6, false, false);
            const uint2v s57 = __builtin_amdgcn_permlane32_swap(u5, u7, false, false);

            union { unsigned int u[4]; bf16x8 v; } pa0, pa1;
            pa0.u[0] = s02.x; pa0.u[1] = s13.x; pa0.u[2] = s02.y; pa0.u[3] = s13.y;
            pa1.u[0] = s46.x; pa1.u[1] = s57.x; pa1.u[2] = s46.y; pa1.u[3] = s57.y;

            __builtin_amdgcn_s_setprio(1);
            #pragma unroll
            for (int kc = 0; kc < 2; kc++) {
                const bf16x8 pav = (kc == 0) ? pa0.v : pa1.v;
                #pragma unroll
                for (int dblk = 0; dblk < 2; dblk++) {
                    bf16x8 vf = *(const bf16x8*)(Vs + (dblk * 32 + l32) * LDV + blk * 32 + kc * 16 + hi * 8);
                    o_acc[dblk] = __builtin_amdgcn_mfma_f32_32x32x16_bf16(pav, vf, o_acc[dblk], 0, 0, 0);
                }
            }
            __builtin_amdgcn_s_setprio(0);
        }
    }

    {
        float ls = lsum;
        ls += __shfl_xor(ls, 32, 64);
        Lsum[wave][l32] = 1.0f / ls;
    }
    __builtin_amdgcn_s_waitcnt(0xC07F);

    #pragma unroll
    for (int r = 0; r < 16; r++) {
        const int qr = (r & 3) + 8 * (r >> 2) + 4 * hi;
        const float rl = Lsum[wave][qr];
        const size_t orow = (size_t)(b * SS + q0 + qr) * EE + h * DHH + l32;
        AO[orow]      = f2bf(o_acc[0][r] * rl);
        AO[orow + 32] = f2bf(o_acc[1][r] * rl);
    }
}

// ---------------------------------------------------------------------------
// R16 aliasing plan (stream order makes every alias race-free):
//   ws (40 MB):  [Wb 8 | Qb 8 | Kc 8 | Vtc 8 | Xvc 8]
//                Xvc (compacted V input) dead after proj GEMM; attn writes
//                AO over it.
//   d_out (16 MB): phase1 [Xq 8 | Xkc 8] (dead after proj GEMM); final
//                out-GEMM overwrites with the real output.
// Pipeline: cvt -> gather -> proj GEMM (Q full; K,V compacted; V transposed
// epilogue) -> attn -> out GEMM. compact_kernel deleted.
// ---------------------------------------------------------------------------
extern "C" void kernel_launch(void* const* d_in, const int* in_sizes, int n_in,
                              void* d_out, int out_size, void* d_ws, size_t ws_size,
                              hipStream_t stream)
{
    (void)in_sizes; (void)n_in; (void)out_size; (void)ws_size;
    const float* queries = (const float*)d_in[0];
    const float* keys    = (const float*)d_in[1];
    const float* values  = (const float*)d_in[2];
    const int*   mask    = (const int*)d_in[3];
    const float* Wq      = (const float*)d_in[4];
    const float* Wk      = (const float*)d_in[5];
    const float* Wv      = (const float*)d_in[6];
    const float* Wo      = (const float*)d_in[7];
    const float* bo      = (const float*)d_in[8];

    const size_t NE = (size_t)BB * SS * EE;          // 4.19M elements
    const size_t WE = (size_t)EE * EE;               // 1.05M elements

    unsigned short* Wb  = (unsigned short*)d_ws;     // [0,8) MB
    unsigned short* Qb  = Wb + 4 * WE;               // [8,16)
    unsigned short* Kc  = Qb + NE;                   // [16,24)
    unsigned short* Vtc = Kc + NE;                   // [24,32)
    unsigned short* Xvc = Vtc + NE;                  // [32,40)
    unsigned short* AOb = Xvc;                       // alias: Xvc dead after proj

    unsigned short* Xq  = (unsigned short*)d_out;    // [0,8) MB (scratch phase)
    unsigned short* Xkc = Xq + NE;                   // [8,16) (scratch phase)

    const int M = BB * SS, N = EE, K = EE;
    // 1/sqrt(2048) * log2(e): softmax exp computed as exp2 of pre-scaled score
    const float qscale = 0.022097086912079608f * 1.4426950408889634f;

    cvt_kernel<<<dim3(2048, 5), 256, 0, stream>>>(
        Wq, Wk, Wv, Wo, queries, Wb, Xq);

    gather_kernel<<<dim3(SS / 64, BB, 2), 256, 0, stream>>>(
        keys, values, mask, Xkc, Xvc);

    dim3 gproj(N / 128, M / 128, 3);
    gemm_xwt<128, 128, true><<<gproj, 256, 0, stream>>>(
        Xq, Xkc, Xvc, Wb, Wb + WE, Wb + 2 * WE,
        (void*)Qb, (void*)Kc, (void*)Vtc, nullptr, M, N, K,
        qscale, 1.0f, 1.0f);

    attn_kernel<<<dim3(512), 256, 0, stream>>>(Qb, Kc, Vtc, mask, AOb);

    dim3 gout(N / 64, M / 128, 1);
    gemm_xwt<128, 64, false><<<gout, 256, 0, stream>>>(
        AOb, AOb, AOb, Wb + 3 * WE, Wb + 3 * WE, Wb + 3 * WE,
        d_out, d_out, d_out, bo, M, N, K, 1.0f, 1.0f, 1.0f);
}